// Round 5
// baseline (524.535 us; speedup 1.0000x reference)
//
#include <hip/hip_runtime.h>

#define IC 1152   // input caps
#define IS 8      // input cap size
#define OC 10     // output caps
#define OS 16     // output cap size
#define OD 160    // OC*OS
#define SQ_EPS 1e-8f
#define NCH 18    // cap chunks (1152 / 64)
#define SRED_STRIDE 165

typedef _Float16 half8 __attribute__((ext_vector_type(8)));
typedef float f32x4 __attribute__((ext_vector_type(4)));

// =========================================================================
// prep_w: WF fragment layout for A-operand of mfma_f32_16x16x32_f16.
// lanes 0..15 hold W[cap][i][j*16+o], i=0..7 (16B per lane).
// =========================================================================
__global__ __launch_bounds__(160) void prep_w(const float* __restrict__ W,
                                              uint4* __restrict__ WF) {
  int cap = blockIdx.x;
  int j = threadIdx.x >> 4;
  int lp = threadIdx.x & 15;
  union { _Float16 h[8]; uint4 u; } pk;
#pragma unroll
  for (int i = 0; i < 8; i++)
    pk.h[i] = (_Float16)W[(size_t)cap * (IS * OD) + i * OD + j * 16 + lp];
  WF[((size_t)cap * OC + j) * 16 + lp] = pk.u;
}

// =========================================================================
// pass_mfma: block = 16 b x 64 caps (4 waves x 16 caps).
// uT(16o x 16b) = mfma(W-frag, x-frag); logits in-reg + 2 shuffles;
// per-lane softmax; weighted accumulate; LDS-atomic reduce; plain stores
// to s_part[b][ch][160] (no global atomics).
// =========================================================================
template <bool PASS0>
__global__ __launch_bounds__(256) void pass_mfma(
    const float* __restrict__ x, const uint4* __restrict__ WF,
    const float* __restrict__ bij, const float* __restrict__ Vsum,
    float* __restrict__ s_part, int Bn) {
  int b0 = blockIdx.x * 16;
  int ch = blockIdx.y;
  int cap0 = ch * 64;
  int tid = threadIdx.x;
  int wid = tid >> 6;
  int lane = tid & 63;
  int bl = lane & 15;        // b column this lane owns
  int og = (lane >> 4) * 4;  // o-quad base of this lane's C rows
  int gb = b0 + bl;
  bool bok = gb < Bn;

  __shared__ __align__(16) uint4 xlh[64 * 16];      // 16 KB f16-packed x
  __shared__ float sred[16 * SRED_STRIDE];          // 10.5 KB

  // zero the reduce buffer
  for (int e = tid; e < 16 * SRED_STRIDE; e += 256) sred[e] = 0.f;

  // ---- stage x tile as packed f16, XOR-swizzled on the b index ----
  for (int e = tid; e < 64 * 16; e += 256) {
    int cc = e & 63, bb = e >> 6;
    int b = b0 + bb;
    float xf[8] = {0, 0, 0, 0, 0, 0, 0, 0};
    if (b < Bn) {
      *(float4*)&xf[0] = *(const float4*)&x[((size_t)b * IC + cap0 + cc) * IS];
      *(float4*)&xf[4] =
          *(const float4*)&x[((size_t)b * IC + cap0 + cc) * IS + 4];
    }
    union { _Float16 h[8]; uint4 u; } pk;
#pragma unroll
    for (int s = 0; s < 8; s++) pk.h[s] = (_Float16)xf[s];
    xlh[cc * 16 + (bb ^ (cc & 15))] = pk.u;
  }
  __syncthreads();

  // ---- Vsum slice for this lane ----
  f32x4 vs4[OC];
#pragma unroll
  for (int j = 0; j < OC; j++) vs4[j] = (f32x4){0.f, 0.f, 0.f, 0.f};
  if (!PASS0 && bok) {
    const float* vrow = Vsum + (size_t)gb * OD;
#pragma unroll
    for (int j = 0; j < OC; j++) {
      float4 t = *(const float4*)(vrow + j * 16 + og);
      vs4[j] = (f32x4){t.x, t.y, t.z, t.w};
    }
  }

  f32x4 sacc[OC];
#pragma unroll
  for (int j = 0; j < OC; j++) sacc[j] = (f32x4){0.f, 0.f, 0.f, 0.f};

  for (int c = 0; c < 16; ++c) {
    int cc = wid * 16 + c;  // cap-local, wave-uniform
    int cap = cap0 + cc;

    // B-operand (x): lanes 0..15 real, others zero => A's k>=8 junk is nulled
    union { uint4 u; half8 h; } xb;
    xb.u = xlh[cc * 16 + ((lane < 16 ? lane : 0) ^ (cc & 15))];
    if (lane >= 16) xb.u = make_uint4(0, 0, 0, 0);

    // 10 MFMAs: uT_j = WjT * xT (A unmasked: junk k>=8 multiplies zero)
    f32x4 uf[OC];
#pragma unroll
    for (int j = 0; j < OC; j++) {
      union { uint4 u; half8 h; } wa;
      wa.u = WF[((size_t)cap * OC + j) * 16 + (lane & 15)];
      f32x4 z = {0.f, 0.f, 0.f, 0.f};
      uf[j] = __builtin_amdgcn_mfma_f32_16x16x32_f16(wa.h, xb.h, z, 0, 0, 0);
    }

    // logits
    float l[OC];
#pragma unroll
    for (int j = 0; j < OC; j++) {
      float bj = bij[cap * OC + j];  // wave-uniform -> scalar load
      if (PASS0) {
        l[j] = bj;
      } else {
        float t = uf[j].x * vs4[j].x + uf[j].y * vs4[j].y +
                  uf[j].z * vs4[j].z + uf[j].w * vs4[j].w;
        t += __shfl_xor(t, 16, 64);
        t += __shfl_xor(t, 32, 64);
        l[j] = bj + t;
      }
    }
    // softmax over j (per lane)
    float m = l[0];
#pragma unroll
    for (int j = 1; j < OC; j++) m = fmaxf(m, l[j]);
    float sum = 0.f, cexp[OC];
#pragma unroll
    for (int j = 0; j < OC; j++) {
      cexp[j] = __expf(l[j] - m);
      sum += cexp[j];
    }
    float inv = 1.f / sum;
#pragma unroll
    for (int j = 0; j < OC; j++) {
      float cj = cexp[j] * inv;
      sacc[j].x += cj * uf[j].x;
      sacc[j].y += cj * uf[j].y;
      sacc[j].z += cj * uf[j].z;
      sacc[j].w += cj * uf[j].w;
    }
  }

  // ---- cross-wave reduce via LDS float atomics (<=2-way bank pattern) ----
  float* sw = &sred[bl * SRED_STRIDE];
#pragma unroll
  for (int j = 0; j < OC; j++) {
    atomicAdd(&sw[j * 16 + og + 0], sacc[j].x);
    atomicAdd(&sw[j * 16 + og + 1], sacc[j].y);
    atomicAdd(&sw[j * 16 + og + 2], sacc[j].z);
    atomicAdd(&sw[j * 16 + og + 3], sacc[j].w);
  }
  __syncthreads();

  // ---- plain coalesced stores to this chunk's partial slice ----
  for (int e = tid; e < 16 * OD; e += 256) {
    int bb = e / OD, d = e - bb * OD;
    int g = b0 + bb;
    if (g < Bn)
      s_part[((size_t)g * NCH + ch) * OD + d] = sred[bb * SRED_STRIDE + d];
  }
}

// =========================================================================
// reduce_squash_part: sum 18 chunk partials, squash, update Vsum / output.
// mode: 0 = Vsum = v ; 1 = Vsum += v ; 2 = out = v (final)
// =========================================================================
__global__ __launch_bounds__(192) void reduce_squash_part(
    const float* __restrict__ s_part, float* __restrict__ Vsum,
    float* __restrict__ out, int mode) {
  int b = blockIdx.x;
  int tid = threadIdx.x;
  __shared__ float sl[OD];
  __shared__ float sc[OC];
  if (tid < OD) {
    float s = 0.f;
#pragma unroll
    for (int chk = 0; chk < NCH; chk++)
      s += s_part[((size_t)b * NCH + chk) * OD + tid];
    sl[tid] = s;
  }
  __syncthreads();
  if (tid < OC) {
    float sq = 0.f;
#pragma unroll
    for (int d = 0; d < OS; d++) {
      float v = sl[tid * OS + d];
      sq += v * v;
    }
    sc[tid] = (sq / (1.f + sq)) / sqrtf(sq + SQ_EPS);
  }
  __syncthreads();
  if (tid < OD) {
    float v = sl[tid] * sc[tid >> 4];
    if (mode == 2)
      out[(size_t)b * OD + tid] = v;
    else if (mode == 0)
      Vsum[(size_t)b * OD + tid] = v;
    else
      Vsum[(size_t)b * OD + tid] += v;
  }
}

// =========================================================================
// Monolithic fallback (tiny ws) — proven correct path.
// =========================================================================
__global__ __launch_bounds__(256) void routing_fallback(
    const float* __restrict__ x, const float* __restrict__ W,
    const float* __restrict__ bij, float* __restrict__ out) {
  int b = blockIdx.x;
  int tid = threadIdx.x;
  int wid = tid >> 6;
  int lane = tid & 63;
  int dq = lane & 3;
  int slot = wid * 16 + (lane >> 2);

  __shared__ __align__(16) float Vs[OD];
  __shared__ __align__(16) float sred2[4][OD];
  __shared__ float sc[OC];

  if (tid < OD) Vs[tid] = 0.f;
  __syncthreads();

  for (int pass = 0; pass < 4; ++pass) {
    float4 vsr[OC];
#pragma unroll
    for (int j = 0; j < OC; j++) vsr[j] = *(const float4*)&Vs[j * 16 + dq * 4];
    float4 sp[OC];
#pragma unroll
    for (int j = 0; j < OC; j++) sp[j] = make_float4(0.f, 0.f, 0.f, 0.f);

    for (int r = 0; r < IC / 64; ++r) {
      int cap = r * 64 + slot;
      float xr[8];
#pragma unroll
      for (int s = 0; s < 8; s++) xr[s] = x[((size_t)b * IC + cap) * IS + s];
      float4 u[OC];
#pragma unroll
      for (int j = 0; j < OC; j++) {
        float4 acc = make_float4(0.f, 0.f, 0.f, 0.f);
#pragma unroll
        for (int s = 0; s < 8; s++) {
          const float4 w =
              *(const float4*)&W[((size_t)cap * IS + s) * OD + j * 16 + dq * 4];
          acc.x += xr[s] * w.x;
          acc.y += xr[s] * w.y;
          acc.z += xr[s] * w.z;
          acc.w += xr[s] * w.w;
        }
        u[j] = acc;
      }
      float l[OC];
#pragma unroll
      for (int j = 0; j < OC; j++) {
        float a = u[j].x * vsr[j].x + u[j].y * vsr[j].y + u[j].z * vsr[j].z +
                  u[j].w * vsr[j].w;
        a += __shfl_xor(a, 1, 64);
        a += __shfl_xor(a, 2, 64);
        l[j] = bij[cap * OC + j] + a;
      }
      float m = l[0];
#pragma unroll
      for (int j = 1; j < OC; j++) m = fmaxf(m, l[j]);
      float sum = 0.f, c[OC];
#pragma unroll
      for (int j = 0; j < OC; j++) {
        c[j] = __expf(l[j] - m);
        sum += c[j];
      }
      float inv = 1.f / sum;
#pragma unroll
      for (int j = 0; j < OC; j++) {
        float ccv = c[j] * inv;
        sp[j].x += ccv * u[j].x;
        sp[j].y += ccv * u[j].y;
        sp[j].z += ccv * u[j].z;
        sp[j].w += ccv * u[j].w;
      }
    }
#pragma unroll
    for (int mask = 4; mask <= 32; mask <<= 1) {
#pragma unroll
      for (int j = 0; j < OC; j++) {
        sp[j].x += __shfl_xor(sp[j].x, mask, 64);
        sp[j].y += __shfl_xor(sp[j].y, mask, 64);
        sp[j].z += __shfl_xor(sp[j].z, mask, 64);
        sp[j].w += __shfl_xor(sp[j].w, mask, 64);
      }
    }
    if (lane < 4) {
#pragma unroll
      for (int j = 0; j < OC; j++)
        *(float4*)&sred2[wid][j * 16 + dq * 4] = sp[j];
    }
    __syncthreads();
    if (tid < OD) {
      float s = sred2[0][tid] + sred2[1][tid] + sred2[2][tid] + sred2[3][tid];
      sred2[0][tid] = s;
    }
    __syncthreads();
    if (tid < OC) {
      float sq = 0.f;
#pragma unroll
      for (int d = 0; d < OS; d++) {
        float v = sred2[0][tid * OS + d];
        sq += v * v;
      }
      sc[tid] = (sq / (1.f + sq)) / sqrtf(sq + SQ_EPS);
    }
    __syncthreads();
    if (tid < OD) {
      float vv = sred2[0][tid] * sc[tid >> 4];
      if (pass < 3)
        Vs[tid] += vv;
      else
        out[(size_t)b * OD + tid] = vv;
    }
    __syncthreads();
  }
}

// =========================================================================
extern "C" void kernel_launch(void* const* d_in, const int* in_sizes, int n_in,
                              void* d_out, int out_size, void* d_ws,
                              size_t ws_size, hipStream_t stream) {
  const float* x = (const float*)d_in[0];    // (B, 1152, 8)
  const float* W = (const float*)d_in[1];    // (1152, 8, 160)
  const float* bij = (const float*)d_in[2];  // (1152, 10)
  float* out = (float*)d_out;                // (B, 10, 16)

  int Bn = in_sizes[0] / (IC * IS);
  size_t buf = (size_t)Bn * OD * sizeof(float);
  size_t wf_bytes = (size_t)IC * OC * 16 * 16;           // 2.95 MB
  size_t spart_bytes = (size_t)Bn * NCH * OD * sizeof(float);  // 11.8 MB

  if (ws_size >= wf_bytes + spart_bytes + buf) {
    uint4* WF = (uint4*)d_ws;
    float* s_part = (float*)((char*)d_ws + wf_bytes);
    float* Vs = (float*)((char*)d_ws + wf_bytes + spart_bytes);

    prep_w<<<IC, 160, 0, stream>>>(W, WF);

    dim3 pg((Bn + 15) / 16, NCH);
    pass_mfma<true><<<pg, 256, 0, stream>>>(x, WF, bij, nullptr, s_part, Bn);
    reduce_squash_part<<<Bn, 192, 0, stream>>>(s_part, Vs, out, 0);
    pass_mfma<false><<<pg, 256, 0, stream>>>(x, WF, bij, Vs, s_part, Bn);
    reduce_squash_part<<<Bn, 192, 0, stream>>>(s_part, Vs, out, 1);
    pass_mfma<false><<<pg, 256, 0, stream>>>(x, WF, bij, Vs, s_part, Bn);
    reduce_squash_part<<<Bn, 192, 0, stream>>>(s_part, Vs, out, 1);
    pass_mfma<false><<<pg, 256, 0, stream>>>(x, WF, bij, Vs, s_part, Bn);
    reduce_squash_part<<<Bn, 192, 0, stream>>>(s_part, Vs, out, 2);
  } else {
    routing_fallback<<<Bn, 256, 0, stream>>>(x, W, bij, out);
  }
}

// Round 6
// 482.823 us; speedup vs baseline: 1.0864x; 1.0864x over previous
//
#include <hip/hip_runtime.h>

#define IC 1152   // input caps
#define IS 8      // input cap size
#define OC 10     // output caps
#define OS 16     // output cap size
#define OD 160    // OC*OS
#define SQ_EPS 1e-8f
#define NCH 18    // cap chunks (1152 / 64)
#define SRED_STRIDE 165

typedef _Float16 half8 __attribute__((ext_vector_type(8)));
typedef float f32x4 __attribute__((ext_vector_type(4)));

// =========================================================================
// prep_w: WF fragment layout for A-operand of mfma_f32_16x16x32_f16.
// lanes 0..15 hold W[cap][i][j*16+o], i=0..7 (16B per lane).
// =========================================================================
__global__ __launch_bounds__(160) void prep_w(const float* __restrict__ W,
                                              uint4* __restrict__ WF) {
  int cap = blockIdx.x;
  int j = threadIdx.x >> 4;
  int lp = threadIdx.x & 15;
  union { _Float16 h[8]; uint4 u; } pk;
#pragma unroll
  for (int i = 0; i < 8; i++)
    pk.h[i] = (_Float16)W[(size_t)cap * (IS * OD) + i * OD + j * 16 + lp];
  WF[((size_t)cap * OC + j) * 16 + lp] = pk.u;
}

// =========================================================================
// pass_mfma: block = 16 b x 64 caps (4 waves x 16 caps).
// Fully-unrolled cap loop with explicit 1-cap-ahead prefetch of the 10 WF
// fragments (ping-pong register buffers, static indices). Softmax VALU
// hides the prefetch latency; wait on current fragments is a counted vmcnt.
// =========================================================================
template <bool PASS0>
__global__ __launch_bounds__(256) void pass_mfma(
    const float* __restrict__ x, const uint4* __restrict__ WF,
    const float* __restrict__ bij, const float* __restrict__ Vsum,
    float* __restrict__ s_part, int Bn) {
  int b0 = blockIdx.x * 16;
  int ch = blockIdx.y;
  int cap0 = ch * 64;
  int tid = threadIdx.x;
  int wid = tid >> 6;
  int lane = tid & 63;
  int bl = lane & 15;        // b column this lane owns
  int og = (lane >> 4) * 4;  // o-quad base of this lane's C rows
  int gb = b0 + bl;
  bool bok = gb < Bn;

  __shared__ __align__(16) uint4 xlh[64 * 16];  // 16 KB f16-packed x
  __shared__ float sred[16 * SRED_STRIDE];      // 10.5 KB
  __shared__ float bijl[64 * OC];               // 2.5 KB

  // zero the reduce buffer; stage bij rows for this chunk
  for (int e = tid; e < 16 * SRED_STRIDE; e += 256) sred[e] = 0.f;
  for (int e = tid; e < 64 * OC; e += 256)
    bijl[e] = bij[(size_t)cap0 * OC + e];

  // ---- stage x tile as packed f16, XOR-swizzled on the b index ----
  for (int e = tid; e < 64 * 16; e += 256) {
    int cc = e & 63, bb = e >> 6;
    int b = b0 + bb;
    float xf[8] = {0, 0, 0, 0, 0, 0, 0, 0};
    if (b < Bn) {
      *(float4*)&xf[0] = *(const float4*)&x[((size_t)b * IC + cap0 + cc) * IS];
      *(float4*)&xf[4] =
          *(const float4*)&x[((size_t)b * IC + cap0 + cc) * IS + 4];
    }
    union { _Float16 h[8]; uint4 u; } pk;
#pragma unroll
    for (int s = 0; s < 8; s++) pk.h[s] = (_Float16)xf[s];
    xlh[cc * 16 + (bb ^ (cc & 15))] = pk.u;
  }
  __syncthreads();

  // ---- Vsum slice for this lane (loop-invariant, keep in registers) ----
  f32x4 vs4[OC];
#pragma unroll
  for (int j = 0; j < OC; j++) vs4[j] = (f32x4){0.f, 0.f, 0.f, 0.f};
  if (!PASS0 && bok) {
    const float* vrow = Vsum + (size_t)gb * OD;
#pragma unroll
    for (int j = 0; j < OC; j++) {
      float4 t = *(const float4*)(vrow + j * 16 + og);
      vs4[j] = (f32x4){t.x, t.y, t.z, t.w};
    }
  }

  f32x4 sacc[OC];
#pragma unroll
  for (int j = 0; j < OC; j++) sacc[j] = (f32x4){0.f, 0.f, 0.f, 0.f};

  // per-wave WF base: cap stride is OC*16 uint4s (=160)
  const uint4* wfp =
      WF + (size_t)(cap0 + wid * 16) * (OC * 16) + (lane & 15);

  // prologue: load cap (wid*16 + 0)'s 10 fragments
  uint4 wbuf[2][OC];
#pragma unroll
  for (int j = 0; j < OC; j++) wbuf[0][j] = wfp[j * 16];

#pragma unroll
  for (int c = 0; c < 16; ++c) {
    const int cur = c & 1;  // compile-time after unroll
    int cc = wid * 16 + c;

    // issue next cap's fragment loads FIRST (stay in flight through softmax)
    if (c < 15) {
#pragma unroll
      for (int j = 0; j < OC; j++)
        wbuf[cur ^ 1][j] = wfp[(c + 1) * (OC * 16) + j * 16];
    }

    // B-operand (x): lanes 0..15 real, others zero => A's k>=8 junk nulled
    union { uint4 u; half8 h; } xb;
    xb.u = xlh[cc * 16 + ((lane < 16 ? lane : 0) ^ (cc & 15))];
    if (lane >= 16) xb.u = make_uint4(0, 0, 0, 0);

    // 10 MFMAs: uT_j = WjT * xT  (waits vmcnt(10): current batch only)
    f32x4 uf[OC];
#pragma unroll
    for (int j = 0; j < OC; j++) {
      union { uint4 u; half8 h; } wa;
      wa.u = wbuf[cur][j];
      f32x4 z = {0.f, 0.f, 0.f, 0.f};
      uf[j] = __builtin_amdgcn_mfma_f32_16x16x32_f16(wa.h, xb.h, z, 0, 0, 0);
    }

    // logits
    float l[OC];
#pragma unroll
    for (int j = 0; j < OC; j++) {
      float bj = bijl[cc * OC + j];  // LDS broadcast
      if (PASS0) {
        l[j] = bj;
      } else {
        float t = uf[j].x * vs4[j].x + uf[j].y * vs4[j].y +
                  uf[j].z * vs4[j].z + uf[j].w * vs4[j].w;
        t += __shfl_xor(t, 16, 64);
        t += __shfl_xor(t, 32, 64);
        l[j] = bj + t;
      }
    }
    // softmax over j (per lane) — VALU here covers the prefetch latency
    float m = l[0];
#pragma unroll
    for (int j = 1; j < OC; j++) m = fmaxf(m, l[j]);
    float sum = 0.f, cexp[OC];
#pragma unroll
    for (int j = 0; j < OC; j++) {
      cexp[j] = __expf(l[j] - m);
      sum += cexp[j];
    }
    float inv = 1.f / sum;
#pragma unroll
    for (int j = 0; j < OC; j++) {
      float cj = cexp[j] * inv;
      sacc[j].x += cj * uf[j].x;
      sacc[j].y += cj * uf[j].y;
      sacc[j].z += cj * uf[j].z;
      sacc[j].w += cj * uf[j].w;
    }
  }

  // ---- cross-wave reduce via LDS float atomics (b32: >=2-way free) ----
  float* sw = &sred[bl * SRED_STRIDE];
#pragma unroll
  for (int j = 0; j < OC; j++) {
    atomicAdd(&sw[j * 16 + og + 0], sacc[j].x);
    atomicAdd(&sw[j * 16 + og + 1], sacc[j].y);
    atomicAdd(&sw[j * 16 + og + 2], sacc[j].z);
    atomicAdd(&sw[j * 16 + og + 3], sacc[j].w);
  }
  __syncthreads();

  // ---- plain coalesced stores to this chunk's partial slice ----
  for (int e = tid; e < 16 * OD; e += 256) {
    int bb = e / OD, d = e - bb * OD;
    int g = b0 + bb;
    if (g < Bn)
      s_part[((size_t)g * NCH + ch) * OD + d] = sred[bb * SRED_STRIDE + d];
  }
}

// =========================================================================
// reduce_squash_part: sum 18 chunk partials, squash, update Vsum / output.
// mode: 0 = Vsum = v ; 1 = Vsum += v ; 2 = out = v (final)
// =========================================================================
__global__ __launch_bounds__(192) void reduce_squash_part(
    const float* __restrict__ s_part, float* __restrict__ Vsum,
    float* __restrict__ out, int mode) {
  int b = blockIdx.x;
  int tid = threadIdx.x;
  __shared__ float sl[OD];
  __shared__ float sc[OC];
  if (tid < OD) {
    float s = 0.f;
#pragma unroll
    for (int chk = 0; chk < NCH; chk++)
      s += s_part[((size_t)b * NCH + chk) * OD + tid];
    sl[tid] = s;
  }
  __syncthreads();
  if (tid < OC) {
    float sq = 0.f;
#pragma unroll
    for (int d = 0; d < OS; d++) {
      float v = sl[tid * OS + d];
      sq += v * v;
    }
    sc[tid] = (sq / (1.f + sq)) / sqrtf(sq + SQ_EPS);
  }
  __syncthreads();
  if (tid < OD) {
    float v = sl[tid] * sc[tid >> 4];
    if (mode == 2)
      out[(size_t)b * OD + tid] = v;
    else if (mode == 0)
      Vsum[(size_t)b * OD + tid] = v;
    else
      Vsum[(size_t)b * OD + tid] += v;
  }
}

// =========================================================================
// Monolithic fallback (tiny ws) — proven correct path.
// =========================================================================
__global__ __launch_bounds__(256) void routing_fallback(
    const float* __restrict__ x, const float* __restrict__ W,
    const float* __restrict__ bij, float* __restrict__ out) {
  int b = blockIdx.x;
  int tid = threadIdx.x;
  int wid = tid >> 6;
  int lane = tid & 63;
  int dq = lane & 3;
  int slot = wid * 16 + (lane >> 2);

  __shared__ __align__(16) float Vs[OD];
  __shared__ __align__(16) float sred2[4][OD];
  __shared__ float sc[OC];

  if (tid < OD) Vs[tid] = 0.f;
  __syncthreads();

  for (int pass = 0; pass < 4; ++pass) {
    float4 vsr[OC];
#pragma unroll
    for (int j = 0; j < OC; j++) vsr[j] = *(const float4*)&Vs[j * 16 + dq * 4];
    float4 sp[OC];
#pragma unroll
    for (int j = 0; j < OC; j++) sp[j] = make_float4(0.f, 0.f, 0.f, 0.f);

    for (int r = 0; r < IC / 64; ++r) {
      int cap = r * 64 + slot;
      float xr[8];
#pragma unroll
      for (int s = 0; s < 8; s++) xr[s] = x[((size_t)b * IC + cap) * IS + s];
      float4 u[OC];
#pragma unroll
      for (int j = 0; j < OC; j++) {
        float4 acc = make_float4(0.f, 0.f, 0.f, 0.f);
#pragma unroll
        for (int s = 0; s < 8; s++) {
          const float4 w =
              *(const float4*)&W[((size_t)cap * IS + s) * OD + j * 16 + dq * 4];
          acc.x += xr[s] * w.x;
          acc.y += xr[s] * w.y;
          acc.z += xr[s] * w.z;
          acc.w += xr[s] * w.w;
        }
        u[j] = acc;
      }
      float l[OC];
#pragma unroll
      for (int j = 0; j < OC; j++) {
        float a = u[j].x * vsr[j].x + u[j].y * vsr[j].y + u[j].z * vsr[j].z +
                  u[j].w * vsr[j].w;
        a += __shfl_xor(a, 1, 64);
        a += __shfl_xor(a, 2, 64);
        l[j] = bij[cap * OC + j] + a;
      }
      float m = l[0];
#pragma unroll
      for (int j = 1; j < OC; j++) m = fmaxf(m, l[j]);
      float sum = 0.f, c[OC];
#pragma unroll
      for (int j = 0; j < OC; j++) {
        c[j] = __expf(l[j] - m);
        sum += c[j];
      }
      float inv = 1.f / sum;
#pragma unroll
      for (int j = 0; j < OC; j++) {
        float ccv = c[j] * inv;
        sp[j].x += ccv * u[j].x;
        sp[j].y += ccv * u[j].y;
        sp[j].z += ccv * u[j].z;
        sp[j].w += ccv * u[j].w;
      }
    }
#pragma unroll
    for (int mask = 4; mask <= 32; mask <<= 1) {
#pragma unroll
      for (int j = 0; j < OC; j++) {
        sp[j].x += __shfl_xor(sp[j].x, mask, 64);
        sp[j].y += __shfl_xor(sp[j].y, mask, 64);
        sp[j].z += __shfl_xor(sp[j].z, mask, 64);
        sp[j].w += __shfl_xor(sp[j].w, mask, 64);
      }
    }
    if (lane < 4) {
#pragma unroll
      for (int j = 0; j < OC; j++)
        *(float4*)&sred2[wid][j * 16 + dq * 4] = sp[j];
    }
    __syncthreads();
    if (tid < OD) {
      float s = sred2[0][tid] + sred2[1][tid] + sred2[2][tid] + sred2[3][tid];
      sred2[0][tid] = s;
    }
    __syncthreads();
    if (tid < OC) {
      float sq = 0.f;
#pragma unroll
      for (int d = 0; d < OS; d++) {
        float v = sred2[0][tid * OS + d];
        sq += v * v;
      }
      sc[tid] = (sq / (1.f + sq)) / sqrtf(sq + SQ_EPS);
    }
    __syncthreads();
    if (tid < OD) {
      float vv = sred2[0][tid] * sc[tid >> 4];
      if (pass < 3)
        Vs[tid] += vv;
      else
        out[(size_t)b * OD + tid] = vv;
    }
    __syncthreads();
  }
}

// =========================================================================
extern "C" void kernel_launch(void* const* d_in, const int* in_sizes, int n_in,
                              void* d_out, int out_size, void* d_ws,
                              size_t ws_size, hipStream_t stream) {
  const float* x = (const float*)d_in[0];    // (B, 1152, 8)
  const float* W = (const float*)d_in[1];    // (1152, 8, 160)
  const float* bij = (const float*)d_in[2];  // (1152, 10)
  float* out = (float*)d_out;                // (B, 10, 16)

  int Bn = in_sizes[0] / (IC * IS);
  size_t buf = (size_t)Bn * OD * sizeof(float);
  size_t wf_bytes = (size_t)IC * OC * 16 * 16;                 // 2.95 MB
  size_t spart_bytes = (size_t)Bn * NCH * OD * sizeof(float);  // 11.8 MB

  if (ws_size >= wf_bytes + spart_bytes + buf) {
    uint4* WF = (uint4*)d_ws;
    float* s_part = (float*)((char*)d_ws + wf_bytes);
    float* Vs = (float*)((char*)d_ws + wf_bytes + spart_bytes);

    prep_w<<<IC, 160, 0, stream>>>(W, WF);

    dim3 pg((Bn + 15) / 16, NCH);
    pass_mfma<true><<<pg, 256, 0, stream>>>(x, WF, bij, nullptr, s_part, Bn);
    reduce_squash_part<<<Bn, 192, 0, stream>>>(s_part, Vs, out, 0);
    pass_mfma<false><<<pg, 256, 0, stream>>>(x, WF, bij, Vs, s_part, Bn);
    reduce_squash_part<<<Bn, 192, 0, stream>>>(s_part, Vs, out, 1);
    pass_mfma<false><<<pg, 256, 0, stream>>>(x, WF, bij, Vs, s_part, Bn);
    reduce_squash_part<<<Bn, 192, 0, stream>>>(s_part, Vs, out, 1);
    pass_mfma<false><<<pg, 256, 0, stream>>>(x, WF, bij, Vs, s_part, Bn);
    reduce_squash_part<<<Bn, 192, 0, stream>>>(s_part, Vs, out, 2);
  } else {
    routing_fallback<<<Bn, 256, 0, stream>>>(x, W, bij, out);
  }
}